// Round 17
// baseline (459.548 us; speedup 1.0000x reference)
//
#include <hip/hip_runtime.h>

#define NROWS 16384
#define NFEAT 4096

typedef __attribute__((ext_vector_type(8))) short          bfrag8;  // 8 x bf16
typedef __attribute__((ext_vector_type(4))) float          fvec4;
typedef __attribute__((ext_vector_type(2))) float          fvec2;
typedef __attribute__((ext_vector_type(4))) unsigned short usvec4;
typedef __attribute__((ext_vector_type(8))) unsigned short usvec8;
typedef __attribute__((ext_vector_type(2))) unsigned int   uvec2;
typedef __attribute__((ext_vector_type(4))) unsigned int   uvec4;

// ---- d_ws layout (byte offsets; uses ~320 MiB of the 1 GiB ws) ----
#define WS_P0   ((size_t)0)            // bn0 partials: 1024 sets x 16 KB (bf16 sum|sumsq)
#define WS_P1   ((size_t)16 << 20)     // bn1 partials: 1024 sets x 16 KB
#define WS_SC0  ((size_t)48 << 20)     // f32[4096] scale0
#define WS_SH0  (WS_SC0 + 16384)       // f32[4096] shift0
#define WS_SC1  (WS_SC0 + 32768)       // f32[4096] scale1
#define WS_SH1  (WS_SC0 + 49152)       // f32[4096] shift1
#define WS_C1P  (WS_SC0 + 65536)       // u32[2048] C1 packed bf16-pairs [o][r/2]
#define WS_C2P  (WS_SC0 + 81920)       // u32[2048] C2 packed bf16-pairs
#define WS_T1   ((size_t)64 << 20)     // t1: 16384 rows x 4 KB fp8 e4m3
#define WS_XB   ((size_t)192 << 20)    // xb: bf16(x), 16384 rows x 8 KB

__device__ __forceinline__ unsigned short f2bf_bits(float f) {
  unsigned u = __builtin_bit_cast(unsigned, f);
  u += 0x7FFFu + ((u >> 16) & 1u);          // round-to-nearest-even
  return (unsigned short)(u >> 16);
}
__device__ __forceinline__ float bf2f(unsigned short b) {
  return __builtin_bit_cast(float, ((unsigned)b) << 16);
}
__device__ __forceinline__ usvec4 pack4(fvec4 a) {
  usvec4 p;
#pragma unroll
  for (int e = 0; e < 4; ++e) p[e] = f2bf_bits(a[e]);
  return p;
}
__device__ __forceinline__ fvec4 unpack4(usvec4 p) {
  return fvec4{bf2f(p[0]), bf2f(p[1]), bf2f(p[2]), bf2f(p[3])};
}
// LDS anti-bank-conflict swizzle for scsh (writer AND reader), 64-dword rows.
__device__ __forceinline__ int swz64(int i) { return i ^ (((i >> 6) & 7) << 2); }

// ---------------- BN0 partial sums + x -> bf16 cast ----------------
__global__ __launch_bounds__(256) void k_bn0part(const float* __restrict__ x,
                                                 unsigned short* __restrict__ p0,
                                                 unsigned short* __restrict__ xb) {
  const int t = threadIdx.x, p = blockIdx.x;          // 1024 blocks, 16 rows each
  fvec4 s[4], sq[4];
#pragma unroll
  for (int q = 0; q < 4; ++q) { s[q] = fvec4{0.f,0.f,0.f,0.f}; sq[q] = s[q]; }
  for (int r = p * 16; r < p * 16 + 16; ++r) {
    const fvec4* row = (const fvec4*)(x + (size_t)r * NFEAT);
    usvec4* xrow = (usvec4*)(xb + (size_t)r * NFEAT);
#pragma unroll
    for (int q = 0; q < 4; ++q) {
      fvec4 v = row[t + 256 * q];
      s[q] += v; sq[q] += v * v;
      xrow[t + 256 * q] = pack4(v);
    }
  }
#pragma unroll
  for (int q = 0; q < 4; ++q) {
    int f0 = (t + 256 * q) * 4;
    *(usvec4*)(p0 + (size_t)p * 8192 + f0)        = pack4(s[q]);
    *(usvec4*)(p0 + (size_t)p * 8192 + 4096 + f0) = pack4(sq[q]);
  }
}

// ---------------- shared reduce body: bf16 partials -> f32 scale|shift ----------------
__device__ __forceinline__ void red_body(fvec4 (*red)[16][2],
                                         const unsigned short* __restrict__ parts,
                                         int nsets,
                                         const float* __restrict__ g,
                                         const float* __restrict__ bta,
                                         float* __restrict__ sc_out,
                                         float* __restrict__ sh_out, int j) {
  const int t = threadIdx.x;
  const int fc = t & 15, c = t >> 4;
  const int v = j * 64 + fc * 4;
  fvec4 s = fvec4{0.f,0.f,0.f,0.f}, q = s;
  for (int i = c; i < nsets; i += 16) {
    s += unpack4(*(const usvec4*)(parts + (size_t)i * 8192 + v));
    q += unpack4(*(const usvec4*)(parts + (size_t)i * 8192 + 4096 + v));
  }
  red[c][fc][0] = s; red[c][fc][1] = q;
  __syncthreads();
  if (c == 0) {
    fvec4 S = red[0][fc][0], Q = red[0][fc][1];
#pragma unroll
    for (int k = 1; k < 16; ++k) { S += red[k][fc][0]; Q += red[k][fc][1]; }
    fvec4 SC, SH;
    const float inv = 1.0f / NROWS;
#pragma unroll
    for (int e = 0; e < 4; ++e) {
      float mean = S[e] * inv;
      float var  = Q[e] * inv - mean * mean;
      float scv  = g[v + e] * rsqrtf(var + 1e-3f);
      SC[e] = scv; SH[e] = bta[v + e] - mean * scv;
    }
    *(fvec4*)(sc_out + v) = SC;
    *(fvec4*)(sh_out + v) = SH;
  }
}

// ---------------- prep0: red0 (blocks 0-63) + packed C1/C2 (blocks 64-95) ----------------
__global__ __launch_bounds__(256) void k_prep0(const unsigned short* __restrict__ p0,
                                               const float* __restrict__ g0,
                                               const float* __restrict__ b0,
                                               float* __restrict__ sc0,
                                               float* __restrict__ sh0,
                                               const float* __restrict__ lb1,
                                               const float* __restrict__ rw1,
                                               const float* __restrict__ rb1,
                                               const float* __restrict__ lb2,
                                               const float* __restrict__ rw2,
                                               const float* __restrict__ rb2,
                                               unsigned* __restrict__ c1p,
                                               unsigned* __restrict__ c2p) {
  __shared__ fvec4 red[16][16][2];
  __shared__ float shc[256];
  if (blockIdx.x < 64) {
    red_body(red, p0, 1024, g0, b0, sc0, sh0, blockIdx.x);
  } else {
    const int bb   = blockIdx.x - 64;
    const int idx  = (bb & 15) * 256 + threadIdx.x;   // 0..4095
    const int part = bb >> 4;                          // 0 -> C1, 1 -> C2
    const float* lb = part ? lb2 : lb1;
    const float* rw = part ? rw2 : rw1;
    const float* rb = part ? rb2 : rb1;
    int r = idx >> 6, o = idx & 63;
    float acc = rb[o * 64 + r];
    for (int j = 0; j < 64; ++j) acc += lb[o * 64 + j] * rw[j * 64 + r];
    shc[threadIdx.x] = acc;
    __syncthreads();
    if (!(idx & 64)) {                                 // even r packs (r, r+1)
      float accO = shc[threadIdx.x ^ 64];
      unsigned pk = (unsigned)f2bf_bits(acc) | ((unsigned)f2bf_bits(accO) << 16);
      (part ? c2p : c1p)[o * 32 + (r >> 1)] = pk;
    }
  }
}

// ---------------- bn1stat: t1(fp8) -> bf16 partial sums ----------------
__global__ __launch_bounds__(256) void k_bn1stat(const unsigned char* __restrict__ t1q,
                                                 unsigned short* __restrict__ p1) {
  const int t = threadIdx.x, p = blockIdx.x;          // 1024 blocks, 16 rows each
  float s[16], q[16];
#pragma unroll
  for (int i = 0; i < 16; ++i) { s[i] = 0.f; q[i] = 0.f; }
  for (int r = p * 16; r < p * 16 + 16; ++r) {
    uvec4 v = *(const uvec4*)(t1q + (size_t)r * NFEAT + t * 16);
#pragma unroll
    for (int d = 0; d < 4; ++d) {
      fvec2 lo = __builtin_amdgcn_cvt_pk_f32_fp8((int)v[d], false);
      fvec2 hi = __builtin_amdgcn_cvt_pk_f32_fp8((int)v[d], true);
      float e0 = lo[0], e1 = lo[1], e2 = hi[0], e3 = hi[1];
      s[d*4+0] += e0; q[d*4+0] += e0*e0;
      s[d*4+1] += e1; q[d*4+1] += e1*e1;
      s[d*4+2] += e2; q[d*4+2] += e2*e2;
      s[d*4+3] += e3; q[d*4+3] += e3*e3;
    }
  }
#pragma unroll
  for (int b4 = 0; b4 < 4; ++b4) {
    fvec4 sv{s[b4*4], s[b4*4+1], s[b4*4+2], s[b4*4+3]};
    fvec4 qv{q[b4*4], q[b4*4+1], q[b4*4+2], q[b4*4+3]};
    *(usvec4*)(p1 + (size_t)p * 8192 + t * 16 + b4 * 4)        = pack4(sv);
    *(usvec4*)(p1 + (size_t)p * 8192 + 4096 + t * 16 + b4 * 4) = pack4(qv);
  }
}

// ---------------- red1: bn1 partials -> scale1|shift1 ----------------
__global__ __launch_bounds__(256) void k_red1(const unsigned short* __restrict__ p1,
                                              const float* __restrict__ g1,
                                              const float* __restrict__ b1,
                                              float* __restrict__ sc1,
                                              float* __restrict__ sh1) {
  __shared__ fvec4 red[16][16][2];
  red_body(red, p1, 1024, g1, b1, sc1, sh1, blockIdx.x);
}

// ---------------- kron: ONE WAVE PER ROW, fp8 V^T in LDS (32 KB total) ----------------
// LDS = vt 4x4KB + scsh 16KB = 32 KB -> up to 5 blocks/CU (4 by VGPR<=128);
// grid 1024 (4 rows/wave) makes 16 waves/CU reachable — 2x the r16 wave count.
// V^T stored fp8 e4m3 (exact when re-expanded to bf16; quantization ~= existing
// t1-fp8 rounding, negligible at output). Swizzle: dword ^= (ridx&7)<<2,
// shared by the 1-dword writes and 2-dword reads (XOR bits>=2 keep 8B align).
// LAYER==1: A-src xb(bf16)+BN0 -> t1 fp8.  LAYER==2: A-src t1(fp8)+BN1 -> xb+Z+C2.
template <int LAYER>
__global__ __launch_bounds__(256, 2) void k_kron(const unsigned short* __restrict__ xb,
                                                 const unsigned char* __restrict__ t1r,
                                                 const float* __restrict__ lw,
                                                 const float* __restrict__ rw,
                                                 const float* __restrict__ scv,
                                                 const float* __restrict__ shv,
                                                 const unsigned* __restrict__ cnp,
                                                 unsigned char* __restrict__ t1w,
                                                 float* __restrict__ outf) {
  __shared__ __align__(16) unsigned vt[4][1024];  // per-wave V^T, fp8 (4 KB each)
  __shared__ __align__(16) unsigned scsh[4096];   // {bf16 sc, bf16 sh} packed, swz64
  const int tid = threadIdx.x, bid = blockIdx.x;
  const int w = tid >> 6, l = tid & 63, m = l & 15, g = l >> 4;
  unsigned* vtw = &vt[w][0];

  // ---- prologue staging (one __syncthreads, the only cross-wave barrier) ----
#pragma unroll
  for (int c = 0; c < 16; ++c) {
    int f = tid * 16 + c;                                // 0..4095
    scsh[swz64(f)] = (unsigned)f2bf_bits(scv[f]) | ((unsigned)f2bf_bits(shv[f]) << 16);
  }
  // zero this wave's vt region: residual coverage bug reads 0.0, not garbage
#pragma unroll
  for (int c = 0; c < 4; ++c)
    *(uvec4*)(vtw + l * 16 + c * 4) = uvec4{0u, 0u, 0u, 0u};

  // RW B-frags: frw[rt][ks][i] = RW[ks*32+g*8+i][rt*16+m]
  bfrag8 frw[4][2];
#pragma unroll
  for (int rt = 0; rt < 4; ++rt)
#pragma unroll
    for (int ks = 0; ks < 2; ++ks)
#pragma unroll
      for (int i = 0; i < 8; ++i)
        frw[rt][ks][i] = (short)f2bf_bits(rw[(ks * 32 + g * 8 + i) * 64 + rt * 16 + m]);

  // LW B-frags: flw[ot][ks][i] = LW[ks*32+g*8+i][ot*16+m]
  bfrag8 flw[4][2];
#pragma unroll
  for (int ot = 0; ot < 4; ++ot)
#pragma unroll
    for (int ks = 0; ks < 2; ++ks)
#pragma unroll
      for (int i = 0; i < 8; ++i)
        flw[ot][ks][i] = (short)f2bf_bits(lw[(ks * 32 + g * 8 + i) * 64 + ot * 16 + m]);

  // bias (packed bf16 pairs in VGPRs): cbv[rt2*4+ot] = C[o=ot*16+m][r=rt2*16+g*4 .. +3]
  uvec2 cbv[16];
#pragma unroll
  for (int rt2 = 0; rt2 < 4; ++rt2)
#pragma unroll
    for (int ot = 0; ot < 4; ++ot)
      cbv[rt2 * 4 + ot] = *(const uvec2*)(cnp + (ot * 16 + m) * 32 + rt2 * 8 + g * 2);

  __syncthreads();

  const int r0w = bid * 16 + w * 4;        // this wave's 4 contiguous rows

  usvec8 sA0[8], sA1[8];                   // LAYER1 staging (cur/next row)
  uvec2  sQ0[8], sQ1[8];                   // LAYER2 staging

  if constexpr (LAYER == 1) {
    const usvec8* p = (const usvec8*)(xb + (size_t)r0w * NFEAT);
#pragma unroll
    for (int kt = 0; kt < 4; ++kt)
#pragma unroll
      for (int ks = 0; ks < 2; ++ks)
        sA0[kt * 2 + ks] = p[(kt * 16 + m) * 8 + ks * 4 + g];
  } else {
    const uvec2* p = (const uvec2*)(t1r + (size_t)r0w * NFEAT);
#pragma unroll
    for (int kt = 0; kt < 4; ++kt)
#pragma unroll
      for (int ks = 0; ks < 2; ++ks)
        sQ0[kt * 2 + ks] = p[(kt * 16 + m) * 8 + ks * 4 + g];
  }

  auto row_body = [&](int rrow, usvec8 (&curA)[8], usvec8 (&nxtA)[8],
                      uvec2 (&curQ)[8], uvec2 (&nxtQ)[8], bool pf) {
    // ---- issue next-row loads (hidden under this row's compute) ----
    if (pf) {
      if constexpr (LAYER == 1) {
        const usvec8* p = (const usvec8*)(xb + (size_t)(rrow + 1) * NFEAT);
#pragma unroll
        for (int kt = 0; kt < 4; ++kt)
#pragma unroll
          for (int ks = 0; ks < 2; ++ks)
            nxtA[kt * 2 + ks] = p[(kt * 16 + m) * 8 + ks * 4 + g];
      } else {
        const uvec2* p = (const uvec2*)(t1r + (size_t)(rrow + 1) * NFEAT);
#pragma unroll
        for (int kt = 0; kt < 4; ++kt)
#pragma unroll
          for (int ks = 0; ks < 2; ++ks)
            nxtQ[kt * 2 + ks] = p[(kt * 16 + m) * 8 + ks * 4 + g];
      }
    }
    // LAYER2: issue residual loads for current row (consumed in epilogue)
    usvec4 res[16];
    if constexpr (LAYER == 2) {
#pragma unroll
      for (int ot = 0; ot < 4; ++ot)
#pragma unroll
        for (int rt2 = 0; rt2 < 4; ++rt2)
          res[ot * 4 + rt2] = *(const usvec4*)(xb + (size_t)rrow * NFEAT +
                                               (ot * 16 + m) * 64 + rt2 * 16 + g * 4);
    }

    __builtin_amdgcn_s_setprio(1);

    // ---- mm1: V = X*RW, write V^T (fp8) into private LDS ----
#pragma unroll
    for (int kt = 0; kt < 4; ++kt) {
      bfrag8 fa[2];
#pragma unroll
      for (int ks = 0; ks < 2; ++ks) {
        int f0 = (kt * 16 + m) * 64 + ks * 32 + g * 8;
        uvec4 c0  = *(const uvec4*)&scsh[swz64(f0)];
        uvec4 c1v = *(const uvec4*)&scsh[swz64(f0 + 4)];
        float xs[8];
        if constexpr (LAYER == 1) {
          usvec8 tv = curA[kt * 2 + ks];
#pragma unroll
          for (int i = 0; i < 8; ++i) xs[i] = bf2f(tv[i]);
        } else {
          uvec2 tv = curQ[kt * 2 + ks];
          fvec2 d0 = __builtin_amdgcn_cvt_pk_f32_fp8((int)tv[0], false);
          fvec2 d1 = __builtin_amdgcn_cvt_pk_f32_fp8((int)tv[0], true);
          fvec2 d2 = __builtin_amdgcn_cvt_pk_f32_fp8((int)tv[1], false);
          fvec2 d3 = __builtin_amdgcn_cvt_pk_f32_fp8((int)tv[1], true);
          xs[0]=d0[0]; xs[1]=d0[1]; xs[2]=d1[0]; xs[3]=d1[1];
          xs[4]=d2[0]; xs[5]=d2[1]; xs[6]=d3[0]; xs[7]=d3[1];
        }
        usvec8 u;
#pragma unroll
        for (int i = 0; i < 8; ++i) {
          unsigned dw = (i < 4) ? c0[i] : c1v[i - 4];
          float scf = __builtin_bit_cast(float, dw << 16);
          float shf = __builtin_bit_cast(float, dw & 0xffff0000u);
          u[i] = f2bf_bits(fmaxf(fmaf(xs[i], scf, shf), 0.f));
        }
        fa[ks] = __builtin_bit_cast(bfrag8, u);
      }
#pragma unroll
      for (int rt = 0; rt < 4; ++rt) {
        fvec4 va = fvec4{0.f, 0.f, 0.f, 0.f};
        va = __builtin_amdgcn_mfma_f32_16x16x32_bf16(fa[0], frw[rt][0], va, 0, 0, 0);
        va = __builtin_amdgcn_mfma_f32_16x16x32_bf16(fa[1], frw[rt][1], va, 0, 0, 0);
        // lane holds V[k=kt*16+g*4+e][r=rt*16+m] -> V^T row ridx, k0=kt*16+g*4
        int ridx = rt * 16 + m;
        int dw = ridx * 16 + kt * 4 + g;               // dword index in fp8 V^T
        int dws = dw ^ ((ridx & 7) << 2);
        int pq = __builtin_amdgcn_cvt_pk_fp8_f32(va[0], va[1], 0, false);
        pq     = __builtin_amdgcn_cvt_pk_fp8_f32(va[2], va[3], pq, true);
        vtw[dws] = (unsigned)pq;
      }
    }

    // wave-local fence: vt writes complete before vt reads (same-wave DS in order)
    asm volatile("s_waitcnt lgkmcnt(0)");

    // ---- mm2: Z^T = V^T * LW (fp8 -> bf16 expand, exact) ----
#pragma unroll
    for (int rt2 = 0; rt2 < 4; ++rt2) {
      int ridx = rt2 * 16 + m;
      bfrag8 af[2];
#pragma unroll
      for (int ks = 0; ks < 2; ++ks) {
        int dw0 = ridx * 16 + ks * 8 + g * 2;
        int dws0 = dw0 ^ ((ridx & 7) << 2);            // even, pair-contiguous
        uvec2 rv = *(const uvec2*)&vtw[dws0];
        fvec2 e0 = __builtin_amdgcn_cvt_pk_f32_fp8((int)rv[0], false);
        fvec2 e1 = __builtin_amdgcn_cvt_pk_f32_fp8((int)rv[0], true);
        fvec2 e2 = __builtin_amdgcn_cvt_pk_f32_fp8((int)rv[1], false);
        fvec2 e3 = __builtin_amdgcn_cvt_pk_f32_fp8((int)rv[1], true);
        usvec8 u;
        u[0] = f2bf_bits(e0[0]); u[1] = f2bf_bits(e0[1]);
        u[2] = f2bf_bits(e1[0]); u[3] = f2bf_bits(e1[1]);
        u[4] = f2bf_bits(e2[0]); u[5] = f2bf_bits(e2[1]);
        u[6] = f2bf_bits(e3[0]); u[7] = f2bf_bits(e3[1]);
        af[ks] = __builtin_bit_cast(bfrag8, u);
      }
      fvec4 acc[4];
#pragma unroll
      for (int ot = 0; ot < 4; ++ot) {
        acc[ot] = fvec4{0.f, 0.f, 0.f, 0.f};
        acc[ot] = __builtin_amdgcn_mfma_f32_16x16x32_bf16(af[0], flw[ot][0], acc[ot], 0, 0, 0);
        acc[ot] = __builtin_amdgcn_mfma_f32_16x16x32_bf16(af[1], flw[ot][1], acc[ot], 0, 0, 0);
      }
      if (rt2 == 3) __builtin_amdgcn_s_setprio(0);
#pragma unroll
      for (int ot = 0; ot < 4; ++ot) {
        uvec2 cv = cbv[rt2 * 4 + ot];
        fvec4 cb4{__builtin_bit_cast(float, cv[0] << 16),
                  __builtin_bit_cast(float, cv[0] & 0xffff0000u),
                  __builtin_bit_cast(float, cv[1] << 16),
                  __builtin_bit_cast(float, cv[1] & 0xffff0000u)};
        fvec4 z = acc[ot] + cb4;
        int foff = (ot * 16 + m) * 64 + rt2 * 16 + g * 4;
        if constexpr (LAYER == 1) {
          int pq = __builtin_amdgcn_cvt_pk_fp8_f32(z[0], z[1], 0, false);
          pq     = __builtin_amdgcn_cvt_pk_fp8_f32(z[2], z[3], pq, true);
          *(unsigned*)(t1w + (size_t)rrow * NFEAT + foff) = (unsigned)pq;
        } else {
          *(fvec4*)(outf + (size_t)rrow * NFEAT + foff) =
              unpack4(res[ot * 4 + rt2]) + z;
        }
      }
    }
  };

  for (int rp = 0; rp < 2; ++rp) {
    row_body(r0w + 2 * rp,     sA0, sA1, sQ0, sQ1, true);
    row_body(r0w + 2 * rp + 1, sA1, sA0, sQ1, sQ0, rp < 1);
  }
}

extern "C" void kernel_launch(void* const* d_in, const int* in_sizes, int n_in,
                              void* d_out, int out_size, void* d_ws, size_t ws_size,
                              hipStream_t stream) {
  (void)in_sizes; (void)n_in; (void)out_size; (void)ws_size;
  const float* x    = (const float*)d_in[0];
  const float* g0   = (const float*)d_in[1];
  const float* b0   = (const float*)d_in[2];
  const float* g1   = (const float*)d_in[3];
  const float* b1   = (const float*)d_in[4];
  const float* k1lw = (const float*)d_in[5];
  const float* k1lb = (const float*)d_in[6];
  const float* k1rw = (const float*)d_in[7];
  const float* k1rb = (const float*)d_in[8];
  const float* k2lw = (const float*)d_in[9];
  const float* k2lb = (const float*)d_in[10];
  const float* k2rw = (const float*)d_in[11];
  const float* k2rb = (const float*)d_in[12];
  char* ws = (char*)d_ws;

  unsigned short* p0  = (unsigned short*)(ws + WS_P0);
  unsigned short* p1  = (unsigned short*)(ws + WS_P1);
  unsigned char*  t1q = (unsigned char*)(ws + WS_T1);
  unsigned short* xb  = (unsigned short*)(ws + WS_XB);
  float* sc0 = (float*)(ws + WS_SC0);
  float* sh0 = (float*)(ws + WS_SH0);
  float* sc1 = (float*)(ws + WS_SC1);
  float* sh1 = (float*)(ws + WS_SH1);
  unsigned* c1p = (unsigned*)(ws + WS_C1P);
  unsigned* c2p = (unsigned*)(ws + WS_C2P);

  k_bn0part<<<1024, 256, 0, stream>>>(x, p0, xb);
  k_prep0<<<96, 256, 0, stream>>>(p0, g0, b0, sc0, sh0,
                                  k1lb, k1rw, k1rb, k2lb, k2rw, k2rb, c1p, c2p);
  k_kron<1><<<1024, 256, 0, stream>>>(xb, nullptr, k1lw, k1rw, sc0, sh0, c1p,
                                      t1q, nullptr);
  k_bn1stat<<<1024, 256, 0, stream>>>(t1q, p1);
  k_red1<<<64, 256, 0, stream>>>(p1, g1, b1, sc1, sh1);
  k_kron<2><<<1024, 256, 0, stream>>>(xb, t1q, k2lw, k2rw, sc1, sh1, c2p,
                                      t1q, (float*)d_out);
}

// Round 18
// 325.284 us; speedup vs baseline: 1.4128x; 1.4128x over previous
//
#include <hip/hip_runtime.h>

#define NROWS 16384
#define NFEAT 4096

typedef __attribute__((ext_vector_type(8))) short          bfrag8;  // 8 x bf16
typedef __attribute__((ext_vector_type(4))) float          fvec4;
typedef __attribute__((ext_vector_type(2))) float          fvec2;
typedef __attribute__((ext_vector_type(4))) unsigned short usvec4;
typedef __attribute__((ext_vector_type(8))) unsigned short usvec8;
typedef __attribute__((ext_vector_type(2))) unsigned int   uvec2;
typedef __attribute__((ext_vector_type(4))) unsigned int   uvec4;

// ---- d_ws layout (byte offsets; uses ~320 MiB of the 1 GiB ws) ----
#define WS_P0   ((size_t)0)            // bn0 partials: 1024 sets x 16 KB (bf16 sum|sumsq)
#define WS_P1   ((size_t)16 << 20)     // bn1 partials: 1024 sets x 16 KB
#define WS_SC0  ((size_t)48 << 20)     // f32[4096] scale0
#define WS_SH0  (WS_SC0 + 16384)       // f32[4096] shift0
#define WS_SC1  (WS_SC0 + 32768)       // f32[4096] scale1
#define WS_SH1  (WS_SC0 + 49152)       // f32[4096] shift1
#define WS_C1   (WS_SC0 + 65536)       // f32[4096] C1[o][r]
#define WS_C2   (WS_SC0 + 81920)       // f32[4096] C2[o][r]
#define WS_T1   ((size_t)64 << 20)     // t1: 16384 rows x 4 KB fp8 e4m3
#define WS_XB   ((size_t)192 << 20)    // xb: bf16(x), 16384 rows x 8 KB

__device__ __forceinline__ unsigned short f2bf_bits(float f) {
  unsigned u = __builtin_bit_cast(unsigned, f);
  u += 0x7FFFu + ((u >> 16) & 1u);          // round-to-nearest-even
  return (unsigned short)(u >> 16);
}
__device__ __forceinline__ float bf2f(unsigned short b) {
  return __builtin_bit_cast(float, ((unsigned)b) << 16);
}
__device__ __forceinline__ usvec4 pack4(fvec4 a) {
  usvec4 p;
#pragma unroll
  for (int e = 0; e < 4; ++e) p[e] = f2bf_bits(a[e]);
  return p;
}
__device__ __forceinline__ fvec4 unpack4(usvec4 p) {
  return fvec4{bf2f(p[0]), bf2f(p[1]), bf2f(p[2]), bf2f(p[3])};
}
// LDS anti-bank-conflict swizzles (used by BOTH writer and reader).
__device__ __forceinline__ int swz64(int i) { return i ^ (((i >> 6) & 7) << 2); }
__device__ __forceinline__ int swz32(int i) { return i ^ (((i >> 5) & 7) << 2); }

// ---------------- BN0 partial sums + x -> bf16 cast ----------------
__global__ __launch_bounds__(256) void k_bn0part(const float* __restrict__ x,
                                                 unsigned short* __restrict__ p0,
                                                 unsigned short* __restrict__ xb) {
  const int t = threadIdx.x, p = blockIdx.x;          // 1024 blocks, 16 rows each
  fvec4 s[4], sq[4];
#pragma unroll
  for (int q = 0; q < 4; ++q) { s[q] = fvec4{0.f,0.f,0.f,0.f}; sq[q] = s[q]; }
  for (int r = p * 16; r < p * 16 + 16; ++r) {
    const fvec4* row = (const fvec4*)(x + (size_t)r * NFEAT);
    usvec4* xrow = (usvec4*)(xb + (size_t)r * NFEAT);
#pragma unroll
    for (int q = 0; q < 4; ++q) {
      fvec4 v = row[t + 256 * q];
      s[q] += v; sq[q] += v * v;
      xrow[t + 256 * q] = pack4(v);
    }
  }
#pragma unroll
  for (int q = 0; q < 4; ++q) {
    int f0 = (t + 256 * q) * 4;
    *(usvec4*)(p0 + (size_t)p * 8192 + f0)        = pack4(s[q]);
    *(usvec4*)(p0 + (size_t)p * 8192 + 4096 + f0) = pack4(sq[q]);
  }
}

// ---------------- shared reduce body: bf16 partials -> f32 scale|shift ----------------
__device__ __forceinline__ void red_body(fvec4 (*red)[16][2],
                                         const unsigned short* __restrict__ parts,
                                         int nsets,
                                         const float* __restrict__ g,
                                         const float* __restrict__ bta,
                                         float* __restrict__ sc_out,
                                         float* __restrict__ sh_out, int j) {
  const int t = threadIdx.x;
  const int fc = t & 15, c = t >> 4;
  const int v = j * 64 + fc * 4;
  fvec4 s = fvec4{0.f,0.f,0.f,0.f}, q = s;
  for (int i = c; i < nsets; i += 16) {
    s += unpack4(*(const usvec4*)(parts + (size_t)i * 8192 + v));
    q += unpack4(*(const usvec4*)(parts + (size_t)i * 8192 + 4096 + v));
  }
  red[c][fc][0] = s; red[c][fc][1] = q;
  __syncthreads();
  if (c == 0) {
    fvec4 S = red[0][fc][0], Q = red[0][fc][1];
#pragma unroll
    for (int k = 1; k < 16; ++k) { S += red[k][fc][0]; Q += red[k][fc][1]; }
    fvec4 SC, SH;
    const float inv = 1.0f / NROWS;
#pragma unroll
    for (int e = 0; e < 4; ++e) {
      float mean = S[e] * inv;
      float var  = Q[e] * inv - mean * mean;
      float scv  = g[v + e] * rsqrtf(var + 1e-3f);
      SC[e] = scv; SH[e] = bta[v + e] - mean * scv;
    }
    *(fvec4*)(sc_out + v) = SC;
    *(fvec4*)(sh_out + v) = SH;
  }
}

// ---------------- prep0: red0 (blocks 0-63) + C1/C2 (blocks 64-95) ----------------
__global__ __launch_bounds__(256) void k_prep0(const unsigned short* __restrict__ p0,
                                               const float* __restrict__ g0,
                                               const float* __restrict__ b0,
                                               float* __restrict__ sc0,
                                               float* __restrict__ sh0,
                                               const float* __restrict__ lb1,
                                               const float* __restrict__ rw1,
                                               const float* __restrict__ rb1,
                                               const float* __restrict__ lb2,
                                               const float* __restrict__ rw2,
                                               const float* __restrict__ rb2,
                                               float* __restrict__ c1,
                                               float* __restrict__ c2) {
  __shared__ fvec4 red[16][16][2];
  if (blockIdx.x < 64) {
    red_body(red, p0, 1024, g0, b0, sc0, sh0, blockIdx.x);
  } else {
    const int bb   = blockIdx.x - 64;
    const int idx  = (bb & 15) * 256 + threadIdx.x;   // 0..4095
    const int part = bb >> 4;                          // 0 -> C1, 1 -> C2
    const float* lb = part ? lb2 : lb1;
    const float* rw = part ? rw2 : rw1;
    const float* rb = part ? rb2 : rb1;
    int r = idx >> 6, o = idx & 63;
    float acc = rb[o * 64 + r];
    for (int j = 0; j < 64; ++j) acc += lb[o * 64 + j] * rw[j * 64 + r];
    (part ? c2 : c1)[o * 64 + r] = acc;                // C[o][r]
  }
}

// ---------------- bn1stat: t1(fp8) -> bf16 partial sums ----------------
__global__ __launch_bounds__(256) void k_bn1stat(const unsigned char* __restrict__ t1q,
                                                 unsigned short* __restrict__ p1) {
  const int t = threadIdx.x, p = blockIdx.x;          // 1024 blocks, 16 rows each
  float s[16], q[16];
#pragma unroll
  for (int i = 0; i < 16; ++i) { s[i] = 0.f; q[i] = 0.f; }
  for (int r = p * 16; r < p * 16 + 16; ++r) {
    uvec4 v = *(const uvec4*)(t1q + (size_t)r * NFEAT + t * 16);
#pragma unroll
    for (int d = 0; d < 4; ++d) {
      fvec2 lo = __builtin_amdgcn_cvt_pk_f32_fp8((int)v[d], false);
      fvec2 hi = __builtin_amdgcn_cvt_pk_f32_fp8((int)v[d], true);
      float e0 = lo[0], e1 = lo[1], e2 = hi[0], e3 = hi[1];
      s[d*4+0] += e0; q[d*4+0] += e0*e0;
      s[d*4+1] += e1; q[d*4+1] += e1*e1;
      s[d*4+2] += e2; q[d*4+2] += e2*e2;
      s[d*4+3] += e3; q[d*4+3] += e3*e3;
    }
  }
#pragma unroll
  for (int b4 = 0; b4 < 4; ++b4) {
    fvec4 sv{s[b4*4], s[b4*4+1], s[b4*4+2], s[b4*4+3]};
    fvec4 qv{q[b4*4], q[b4*4+1], q[b4*4+2], q[b4*4+3]};
    *(usvec4*)(p1 + (size_t)p * 8192 + t * 16 + b4 * 4)        = pack4(sv);
    *(usvec4*)(p1 + (size_t)p * 8192 + 4096 + t * 16 + b4 * 4) = pack4(qv);
  }
}

// ---------------- red1: bn1 partials -> scale1|shift1 ----------------
__global__ __launch_bounds__(256) void k_red1(const unsigned short* __restrict__ p1,
                                              const float* __restrict__ g1,
                                              const float* __restrict__ b1,
                                              float* __restrict__ sc1,
                                              float* __restrict__ sh1) {
  __shared__ fvec4 red[16][16][2];
  red_body(red, p1, 1024, g1, b1, sc1, sh1, blockIdx.x);
}

// ---------------- kron: ONE WAVE PER ROW, no barriers/sched pins in the loop ----------------
// Per row b: X[k][j] (64x64, post BN+relu, bf16).  mm1: V = X*RW (4 kt x 4 rt tiles).
// V^T staged in this wave's PRIVATE 8KB LDS region. mm1 ds_writes and mm2 ds_reads
// use the SAME element type (unsigned short vectors) so alias analysis keeps program
// order; same-wave DS ops complete in order, and a bare lgkmcnt(0) is kept as a
// cheap belt-and-suspenders. s_setprio(1) wraps the compute core.
// LAYER==1: A-src xb(bf16)+BN0 -> t1 fp8.  LAYER==2: A-src t1(fp8)+BN1 -> xb+Z+C2.
template <int LAYER>
__global__ __launch_bounds__(256, 2) void k_kron(const unsigned short* __restrict__ xb,
                                                 const unsigned char* __restrict__ t1r,
                                                 const float* __restrict__ lw,
                                                 const float* __restrict__ rw,
                                                 const float* __restrict__ scv,
                                                 const float* __restrict__ shv,
                                                 const float* __restrict__ cn,
                                                 unsigned char* __restrict__ t1w,
                                                 float* __restrict__ outf) {
  __shared__ __align__(16) unsigned short vt[4][4096];  // per-wave private V^T (8 KB each)
  __shared__ __align__(16) unsigned scsh[4096];  // dword f: {lo: bf16 sc[f], hi: bf16 sh[f]}, swz64
  __shared__ __align__(16) unsigned cbl[2048];   // dword d: bf16 pair {C[o][2r'],C[o][2r'+1]}, swz32
  const int tid = threadIdx.x, bid = blockIdx.x;
  const int w = tid >> 6, l = tid & 63, m = l & 15, g = l >> 4;
  unsigned short* vtw = &vt[w][0];

  // ---- prologue staging (one __syncthreads, the only cross-wave barrier) ----
#pragma unroll
  for (int c = 0; c < 16; ++c) {
    int f = tid * 16 + c;                                // 0..4095
    scsh[swz64(f)] = (unsigned)f2bf_bits(scv[f]) | ((unsigned)f2bf_bits(shv[f]) << 16);
  }
#pragma unroll
  for (int c = 0; c < 8; ++c) {
    int d = tid * 8 + c;                                 // 0..2047
    int o = d >> 5, pr = (d & 31) * 2;
    cbl[swz32(d)] = (unsigned)f2bf_bits(cn[o * 64 + pr]) |
                    ((unsigned)f2bf_bits(cn[o * 64 + pr + 1]) << 16);
  }
  // zero this wave's vt region: residual coverage bug reads 0.0, not garbage
#pragma unroll
  for (int c = 0; c < 8; ++c)
    *(uvec4*)((char*)vtw + l * 128 + c * 16) = uvec4{0u, 0u, 0u, 0u};

  // RW B-frags: frw[rt][ks][i] = RW[ks*32+g*8+i][rt*16+m]
  bfrag8 frw[4][2];
#pragma unroll
  for (int rt = 0; rt < 4; ++rt)
#pragma unroll
    for (int ks = 0; ks < 2; ++ks)
#pragma unroll
      for (int i = 0; i < 8; ++i)
        frw[rt][ks][i] = (short)f2bf_bits(rw[(ks * 32 + g * 8 + i) * 64 + rt * 16 + m]);

  // LW B-frags: flw[ot][ks][i] = LW[ks*32+g*8+i][ot*16+m]
  bfrag8 flw[4][2];
#pragma unroll
  for (int ot = 0; ot < 4; ++ot)
#pragma unroll
    for (int ks = 0; ks < 2; ++ks)
#pragma unroll
      for (int i = 0; i < 8; ++i)
        flw[ot][ks][i] = (short)f2bf_bits(lw[(ks * 32 + g * 8 + i) * 64 + ot * 16 + m]);

  __syncthreads();

  const int r0w = bid * 32 + w * 8;        // this wave's 8 contiguous rows

  usvec8 sA0[8], sA1[8];                   // LAYER1 staging (cur/next row)
  uvec2  sQ0[8], sQ1[8];                   // LAYER2 staging

  if constexpr (LAYER == 1) {
    const usvec8* p = (const usvec8*)(xb + (size_t)r0w * NFEAT);
#pragma unroll
    for (int kt = 0; kt < 4; ++kt)
#pragma unroll
      for (int ks = 0; ks < 2; ++ks)
        sA0[kt * 2 + ks] = p[(kt * 16 + m) * 8 + ks * 4 + g];
  } else {
    const uvec2* p = (const uvec2*)(t1r + (size_t)r0w * NFEAT);
#pragma unroll
    for (int kt = 0; kt < 4; ++kt)
#pragma unroll
      for (int ks = 0; ks < 2; ++ks)
        sQ0[kt * 2 + ks] = p[(kt * 16 + m) * 8 + ks * 4 + g];
  }

  auto row_body = [&](int rrow, usvec8 (&curA)[8], usvec8 (&nxtA)[8],
                      uvec2 (&curQ)[8], uvec2 (&nxtQ)[8], bool pf) {
    // ---- issue next-row loads (hidden under this row's compute) ----
    if (pf) {
      if constexpr (LAYER == 1) {
        const usvec8* p = (const usvec8*)(xb + (size_t)(rrow + 1) * NFEAT);
#pragma unroll
        for (int kt = 0; kt < 4; ++kt)
#pragma unroll
          for (int ks = 0; ks < 2; ++ks)
            nxtA[kt * 2 + ks] = p[(kt * 16 + m) * 8 + ks * 4 + g];
      } else {
        const uvec2* p = (const uvec2*)(t1r + (size_t)(rrow + 1) * NFEAT);
#pragma unroll
        for (int kt = 0; kt < 4; ++kt)
#pragma unroll
          for (int ks = 0; ks < 2; ++ks)
            nxtQ[kt * 2 + ks] = p[(kt * 16 + m) * 8 + ks * 4 + g];
      }
    }
    // LAYER2: issue residual loads for current row (consumed in epilogue)
    usvec4 res[16];
    if constexpr (LAYER == 2) {
#pragma unroll
      for (int ot = 0; ot < 4; ++ot)
#pragma unroll
        for (int rt2 = 0; rt2 < 4; ++rt2)
          res[ot * 4 + rt2] = *(const usvec4*)(xb + (size_t)rrow * NFEAT +
                                               (ot * 16 + m) * 64 + rt2 * 16 + g * 4);
    }

    __builtin_amdgcn_s_setprio(1);

    // ---- mm1: V = X*RW, write V^T into private LDS ----
#pragma unroll
    for (int kt = 0; kt < 4; ++kt) {
      bfrag8 fa[2];
#pragma unroll
      for (int ks = 0; ks < 2; ++ks) {
        int f0 = (kt * 16 + m) * 64 + ks * 32 + g * 8;
        uvec4 c0  = *(const uvec4*)&scsh[swz64(f0)];
        uvec4 c1v = *(const uvec4*)&scsh[swz64(f0 + 4)];
        float xs[8];
        if constexpr (LAYER == 1) {
          usvec8 tv = curA[kt * 2 + ks];
#pragma unroll
          for (int i = 0; i < 8; ++i) xs[i] = bf2f(tv[i]);
        } else {
          uvec2 tv = curQ[kt * 2 + ks];
          fvec2 d0 = __builtin_amdgcn_cvt_pk_f32_fp8((int)tv[0], false);
          fvec2 d1 = __builtin_amdgcn_cvt_pk_f32_fp8((int)tv[0], true);
          fvec2 d2 = __builtin_amdgcn_cvt_pk_f32_fp8((int)tv[1], false);
          fvec2 d3 = __builtin_amdgcn_cvt_pk_f32_fp8((int)tv[1], true);
          xs[0]=d0[0]; xs[1]=d0[1]; xs[2]=d1[0]; xs[3]=d1[1];
          xs[4]=d2[0]; xs[5]=d2[1]; xs[6]=d3[0]; xs[7]=d3[1];
        }
        usvec8 u;
#pragma unroll
        for (int i = 0; i < 8; ++i) {
          unsigned dw = (i < 4) ? c0[i] : c1v[i - 4];
          float scf = __builtin_bit_cast(float, dw << 16);
          float shf = __builtin_bit_cast(float, dw & 0xffff0000u);
          u[i] = f2bf_bits(fmaxf(fmaf(xs[i], scf, shf), 0.f));
        }
        fa[ks] = __builtin_bit_cast(bfrag8, u);
      }
#pragma unroll
      for (int rt = 0; rt < 4; ++rt) {
        fvec4 va = fvec4{0.f, 0.f, 0.f, 0.f};
        va = __builtin_amdgcn_mfma_f32_16x16x32_bf16(fa[0], frw[rt][0], va, 0, 0, 0);
        va = __builtin_amdgcn_mfma_f32_16x16x32_bf16(fa[1], frw[rt][1], va, 0, 0, 0);
        int ridx = rt * 16 + m;
        int chunk = 2 * kt + (g >> 1);
        int byte = ridx * 128 + ((chunk ^ (ridx & 7)) << 4) + (g & 1) * 8;
        *(usvec4*)((char*)vtw + byte) = pack4(va);
      }
    }

    // belt-and-suspenders: drain this wave's DS queue (near-free; same-wave DS
    // completes in order, and MayAlias keeps the compiler from reordering the
    // mm2 reads above the mm1 writes — no sched_barrier pinning needed).
    asm volatile("s_waitcnt lgkmcnt(0)");

    // ---- mm2: Z^T = V^T * LW (reads same element type as writes -> TBAA-safe) ----
#pragma unroll
    for (int rt2 = 0; rt2 < 4; ++rt2) {
      int ridx = rt2 * 16 + m;
      bfrag8 a0 = __builtin_bit_cast(bfrag8, *(const usvec8*)((const char*)vtw +
                    ridx * 128 + (((0 + g) ^ (ridx & 7)) << 4)));
      bfrag8 a1 = __builtin_bit_cast(bfrag8, *(const usvec8*)((const char*)vtw +
                    ridx * 128 + (((4 + g) ^ (ridx & 7)) << 4)));
      fvec4 acc[4];
#pragma unroll
      for (int ot = 0; ot < 4; ++ot) {
        acc[ot] = fvec4{0.f, 0.f, 0.f, 0.f};
        acc[ot] = __builtin_amdgcn_mfma_f32_16x16x32_bf16(a0, flw[ot][0], acc[ot], 0, 0, 0);
        acc[ot] = __builtin_amdgcn_mfma_f32_16x16x32_bf16(a1, flw[ot][1], acc[ot], 0, 0, 0);
      }
      if (rt2 == 3) __builtin_amdgcn_s_setprio(0);
#pragma unroll
      for (int ot = 0; ot < 4; ++ot) {
        int dcb = (ot * 16 + m) * 32 + rt2 * 8 + 2 * g;
        uvec2 cv = *(const uvec2*)&cbl[swz32(dcb)];
        fvec4 cb4{__builtin_bit_cast(float, cv[0] << 16),
                  __builtin_bit_cast(float, cv[0] & 0xffff0000u),
                  __builtin_bit_cast(float, cv[1] << 16),
                  __builtin_bit_cast(float, cv[1] & 0xffff0000u)};
        fvec4 z = acc[ot] + cb4;
        int foff = (ot * 16 + m) * 64 + rt2 * 16 + g * 4;
        if constexpr (LAYER == 1) {
          int pq = __builtin_amdgcn_cvt_pk_fp8_f32(z[0], z[1], 0, false);
          pq     = __builtin_amdgcn_cvt_pk_fp8_f32(z[2], z[3], pq, true);
          *(unsigned*)(t1w + (size_t)rrow * NFEAT + foff) = (unsigned)pq;
        } else {
          *(fvec4*)(outf + (size_t)rrow * NFEAT + foff) =
              unpack4(res[ot * 4 + rt2]) + z;
        }
      }
    }
  };

  for (int rp = 0; rp < 4; ++rp) {
    row_body(r0w + 2 * rp,     sA0, sA1, sQ0, sQ1, true);
    row_body(r0w + 2 * rp + 1, sA1, sA0, sQ1, sQ0, rp < 3);
  }
}

extern "C" void kernel_launch(void* const* d_in, const int* in_sizes, int n_in,
                              void* d_out, int out_size, void* d_ws, size_t ws_size,
                              hipStream_t stream) {
  (void)in_sizes; (void)n_in; (void)out_size; (void)ws_size;
  const float* x    = (const float*)d_in[0];
  const float* g0   = (const float*)d_in[1];
  const float* b0   = (const float*)d_in[2];
  const float* g1   = (const float*)d_in[3];
  const float* b1   = (const float*)d_in[4];
  const float* k1lw = (const float*)d_in[5];
  const float* k1lb = (const float*)d_in[6];
  const float* k1rw = (const float*)d_in[7];
  const float* k1rb = (const float*)d_in[8];
  const float* k2lw = (const float*)d_in[9];
  const float* k2lb = (const float*)d_in[10];
  const float* k2rw = (const float*)d_in[11];
  const float* k2rb = (const float*)d_in[12];
  char* ws = (char*)d_ws;

  unsigned short* p0  = (unsigned short*)(ws + WS_P0);
  unsigned short* p1  = (unsigned short*)(ws + WS_P1);
  unsigned char*  t1q = (unsigned char*)(ws + WS_T1);
  unsigned short* xb  = (unsigned short*)(ws + WS_XB);
  float* sc0 = (float*)(ws + WS_SC0);
  float* sh0 = (float*)(ws + WS_SH0);
  float* sc1 = (float*)(ws + WS_SC1);
  float* sh1 = (float*)(ws + WS_SH1);
  float* c1  = (float*)(ws + WS_C1);
  float* c2  = (float*)(ws + WS_C2);

  k_bn0part<<<1024, 256, 0, stream>>>(x, p0, xb);
  k_prep0<<<96, 256, 0, stream>>>(p0, g0, b0, sc0, sh0,
                                  k1lb, k1rw, k1rb, k2lb, k2rw, k2rb, c1, c2);
  k_kron<1><<<512, 256, 0, stream>>>(xb, nullptr, k1lw, k1rw, sc0, sh0, c1,
                                     t1q, nullptr);
  k_bn1stat<<<1024, 256, 0, stream>>>(t1q, p1);
  k_red1<<<64, 256, 0, stream>>>(p1, g1, b1, sc1, sh1);
  k_kron<2><<<512, 256, 0, stream>>>(xb, t1q, k2lw, k2rw, sc1, sh1, c2,
                                     t1q, (float*)d_out);
}